// Round 6
// baseline (580.588 us; speedup 1.0000x reference)
//
#include <hip/hip_runtime.h>
#include <hip/hip_bf16.h>
#include <math.h>

// B=2, N=2048, M=1024, H=16, DK=64. fp32 in/out.
// Split-bf16 MFMA everywhere: a*b ~= ah*bh + ah*bl + al*bh (fp32-grade).
// R6 = R5 with the workspace layout bug fixed: x is [4096][1024] (4.19M
// floats), so every plane is 4194304 shorts. Pre-split x only if ws_size
// allows (runtime-constant branch, graph-safe); else R4's proven
// split-on-the-fly staging for the QKV GEMM.

typedef __attribute__((ext_vector_type(8))) short bf16x8;
typedef __attribute__((ext_vector_type(4))) float f32x4;

__device__ __forceinline__ short f2b(float f) {
    union { __hip_bfloat16 h; short s; } u;
    u.h = __float2bfloat16(f);   // RNE
    return u.s;
}
__device__ __forceinline__ float b2f(short s) {
    union { short s; __hip_bfloat16 h; } u;
    u.s = s;
    return __bfloat162float(u.h);
}

// XOR-swizzled element offset inside a [rows][64]-bf16 tile (16B blocks).
__device__ __forceinline__ int sw8(int r, int k8) {       // k8 = octet 0..7
    return (r << 6) + ((k8 ^ (r & 7)) << 3);
}
__device__ __forceinline__ int swe(int r, int k) {        // element-level
    return (r << 6) + (((k >> 3) ^ (r & 7)) << 3) + (k & 7);
}

// split 8 fp32 -> hi/lo bf16x8
__device__ __forceinline__ void split8(const float* v, bf16x8* h8, bf16x8* l8) {
    union { short s[8]; bf16x8 v8; } H, L;
    #pragma unroll
    for (int e = 0; e < 8; ++e) {
        const float f = v[e];
        const short hs = f2b(f);
        H.s[e] = hs;
        L.s[e] = f2b(f - b2f(hs));
    }
    *h8 = H.v8; *l8 = L.v8;
}

// workspace layout (SHORT offsets). Every plane = 4194304 shorts (8 MB).
#define PLANE   4194304UL
#define OFF_WH  (0UL * PLANE)    // [4][1024][1024] W hi (4 matrices = 1 plane)
#define OFF_WL  (1UL * PLANE)
#define OFF_QH  (2UL * PLANE)    // [B,H,N,DK]
#define OFF_QL  (3UL * PLANE)
#define OFF_KH  (4UL * PLANE)
#define OFF_KL  (5UL * PLANE)
#define OFF_VTH (6UL * PLANE)    // [B,H,DK,N]
#define OFF_VTL (7UL * PLANE)
#define OFF_CH  (8UL * PLANE)    // [B,N,M] concat
#define OFF_CL  (9UL * PLANE)
// base end: 10 planes = 83.9 MB (R3/R4-proven size)
#define OFF_XH  (10UL * PLANE)   // [4096][1024] x hi  (optional)
#define OFF_XL  (11UL * PLANE)
#define WS_FULL_BYTES (12UL * PLANE * 2UL)   // 100.7 MB

// ---------------------------------------------------------------------------
// Pre-split weights (always) and x (if xh != nullptr) into hi/lo planes.
// Grid: 4096 blocks (weights only) or 8192 (weights + x).
// ---------------------------------------------------------------------------
__global__ __launch_bounds__(256) void split_wx(
    const float* __restrict__ Wq, const float* __restrict__ Wk,
    const float* __restrict__ Wv, const float* __restrict__ Wo,
    const float* __restrict__ x,
    unsigned short* __restrict__ wh, unsigned short* __restrict__ wl,
    unsigned short* __restrict__ xh, unsigned short* __restrict__ xl)
{
    const int i = blockIdx.x * 256 + threadIdx.x;   // float4 index
    const float* src; unsigned short *dh, *dl; int local;
    if (i < 1048576) {                               // 4 x 262144 float4
        src = (i < 262144) ? Wq : (i < 524288) ? Wk : (i < 786432) ? Wv : Wo;
        local = i & 262143;
        dh = wh + (size_t)(i >> 18) * 1048576;       // per-matrix plane offset
        dl = wl + (size_t)(i >> 18) * 1048576;
    } else {                                         // x: 1048576 float4
        src = x; local = i - 1048576; dh = xh; dl = xl;
    }
    float4 v = ((const float4*)src)[local];
    short4 h, l;
    h.x = f2b(v.x); l.x = f2b(v.x - b2f(h.x));
    h.y = f2b(v.y); l.y = f2b(v.y - b2f(h.y));
    h.z = f2b(v.z); l.z = f2b(v.z - b2f(h.z));
    h.w = f2b(v.w); l.w = f2b(v.w - b2f(h.w));
    ((short4*)dh)[local] = h;
    ((short4*)dl)[local] = l;
}

// ---------------------------------------------------------------------------
// Split-bf16 GEMM: C = A @ W^T + bias.
// A operand: pre-split planes (Ah/Al) if Afp==nullptr, else fp32 Afp with
// on-the-fly split (uniform branch). 128x128 tile, 4 waves, 4x4 frags, BK=64.
// mode 0/1: Q/K planes; mode 2: V^T planes; mode 3: fp32 out + bias.
// ---------------------------------------------------------------------------
__global__ __launch_bounds__(256, 2) void gemm_split(
    const float* __restrict__ Afp,
    const unsigned short* __restrict__ Ah, const unsigned short* __restrict__ Al,
    unsigned short* __restrict__ wsS,
    const float* __restrict__ b0, const float* __restrict__ b1,
    const float* __restrict__ b2, const float* __restrict__ b3,
    float* __restrict__ oout, int modeBase)
{
    __shared__ unsigned short Ash[128 * 64], Asl[128 * 64];
    __shared__ unsigned short Bsh[128 * 64], Bsl[128 * 64];

    const int mode = modeBase + blockIdx.z;
    const unsigned short* Wh = wsS + OFF_WH + (size_t)mode * 1048576;
    const unsigned short* Wl = wsS + OFF_WL + (size_t)mode * 1048576;
    const float* bias = (mode == 0) ? b0 : (mode == 1) ? b1 : (mode == 2) ? b2 : b3;

    const int tid  = threadIdx.x;
    const int lane = tid & 63;
    const int lm   = lane & 15;
    const int quad = lane >> 4;
    const int w    = tid >> 6;
    const int wr   = w >> 1, wc = w & 1;

    const int row0 = blockIdx.y * 128;
    const int col0 = blockIdx.x * 128;

    const int sk8 = tid & 7;      // staging octet
    const int sr0 = tid >> 3;     // staging row 0..31

    f32x4 acc[4][4] = {};

    for (int k0 = 0; k0 < 1024; k0 += 64) {
        if (k0) __syncthreads();
        #pragma unroll
        for (int i = 0; i < 4; ++i) {
            const int r = sr0 + 32 * i;
            if (Afp) {
                float av[8];
                *(float4*)&av[0] = *(const float4*)&Afp[(size_t)(row0 + r) * 1024 + k0 + sk8 * 8];
                *(float4*)&av[4] = *(const float4*)&Afp[(size_t)(row0 + r) * 1024 + k0 + sk8 * 8 + 4];
                bf16x8 ah, al;
                split8(av, &ah, &al);
                *(bf16x8*)&Ash[sw8(r, sk8)] = ah;
                *(bf16x8*)&Asl[sw8(r, sk8)] = al;
            } else {
                *(bf16x8*)&Ash[sw8(r, sk8)] =
                    *(const bf16x8*)&Ah[(size_t)(row0 + r) * 1024 + k0 + sk8 * 8];
                *(bf16x8*)&Asl[sw8(r, sk8)] =
                    *(const bf16x8*)&Al[(size_t)(row0 + r) * 1024 + k0 + sk8 * 8];
            }
            *(bf16x8*)&Bsh[sw8(r, sk8)] =
                *(const bf16x8*)&Wh[(size_t)(col0 + r) * 1024 + k0 + sk8 * 8];
            *(bf16x8*)&Bsl[sw8(r, sk8)] =
                *(const bf16x8*)&Wl[(size_t)(col0 + r) * 1024 + k0 + sk8 * 8];
        }
        __syncthreads();
        #pragma unroll
        for (int ks = 0; ks < 2; ++ks) {
            bf16x8 afh[4], afl[4], bfh[4], bfl[4];
            #pragma unroll
            for (int mi = 0; mi < 4; ++mi) {
                afh[mi] = *(const bf16x8*)&Ash[sw8(wr * 64 + mi * 16 + lm, ks * 4 + quad)];
                afl[mi] = *(const bf16x8*)&Asl[sw8(wr * 64 + mi * 16 + lm, ks * 4 + quad)];
            }
            #pragma unroll
            for (int ni = 0; ni < 4; ++ni) {
                bfh[ni] = *(const bf16x8*)&Bsh[sw8(wc * 64 + ni * 16 + lm, ks * 4 + quad)];
                bfl[ni] = *(const bf16x8*)&Bsl[sw8(wc * 64 + ni * 16 + lm, ks * 4 + quad)];
            }
            #pragma unroll
            for (int mi = 0; mi < 4; ++mi) {
                #pragma unroll
                for (int ni = 0; ni < 4; ++ni) {
                    acc[mi][ni] = __builtin_amdgcn_mfma_f32_16x16x32_bf16(
                        afh[mi], bfh[ni], acc[mi][ni], 0, 0, 0);
                    acc[mi][ni] = __builtin_amdgcn_mfma_f32_16x16x32_bf16(
                        afh[mi], bfl[ni], acc[mi][ni], 0, 0, 0);
                    acc[mi][ni] = __builtin_amdgcn_mfma_f32_16x16x32_bf16(
                        afl[mi], bfh[ni], acc[mi][ni], 0, 0, 0);
                }
            }
        }
    }

    unsigned short* qh  = wsS + OFF_QH;
    unsigned short* ql  = wsS + OFF_QL;
    unsigned short* kh  = wsS + OFF_KH;
    unsigned short* kl  = wsS + OFF_KL;
    unsigned short* vth = wsS + OFF_VTH;
    unsigned short* vtl = wsS + OFF_VTL;

    // epilogue: C/D layout col=lane&15, row=quad*4+reg
    #pragma unroll
    for (int ni = 0; ni < 4; ++ni) {
        const int f = col0 + wc * 64 + ni * 16 + lm;
        const float bv = bias[f];
        const int h = f >> 6, d = f & 63;
        #pragma unroll
        for (int mi = 0; mi < 4; ++mi) {
            #pragma unroll
            for (int j = 0; j < 4; ++j) {
                const int row = row0 + wr * 64 + mi * 16 + quad * 4 + j;
                const float val = acc[mi][ni][j] + bv;
                if (mode == 3) {
                    oout[(size_t)row * 1024 + f] = val;
                } else {
                    const int bb = row >> 11, n = row & 2047;
                    const short hs = f2b(val);
                    const short ls = f2b(val - b2f(hs));
                    if (mode == 2) {
                        const size_t idx = ((size_t)(bb * 16 + h) * 64 + d) * 2048 + n;
                        vth[idx] = hs; vtl[idx] = ls;
                    } else {
                        const size_t idx = ((size_t)(bb * 16 + h) * 2048 + n) * 64 + d;
                        if (mode == 0) { qh[idx] = hs; ql[idx] = ls; }
                        else           { kh[idx] = hs; kl[idx] = ls; }
                    }
                }
            }
        }
    }
}

// ---------------------------------------------------------------------------
// Flash attention, split-bf16 MFMA, deferred softmax normalization.
// Block = (b, h, 128 q-rows); wave w owns rows [w*32, w*32+32) (2 frag strips).
// Grid 512 = exactly 2 blocks/CU (64 KB LDS) -> no occupancy tail.
// Output written as hi/lo bf16 planes (exact fp32 split) for out_gemm.
// ---------------------------------------------------------------------------
__global__ __launch_bounds__(256, 2) void attn_fast(
    const unsigned short* __restrict__ wsS, const float* __restrict__ mask,
    unsigned short* __restrict__ ch, unsigned short* __restrict__ cl)
{
    __shared__ unsigned short Ksh[64 * 64], Ksl[64 * 64];    // [kcol][d]
    __shared__ unsigned short Vth[64 * 64], Vtl[64 * 64];    // [d][k]
    __shared__ unsigned short Psh[4][32 * 64], Psl[4][32 * 64];

    const int tid  = threadIdx.x;
    const int lane = tid & 63;
    const int lm   = lane & 15;
    const int quad = lane >> 4;
    const int w    = tid >> 6;

    const int q0 = blockIdx.x * 128;
    const int h  = blockIdx.y;
    const int b  = blockIdx.z;
    const int bh = b * 16 + h;

    const unsigned short* Qhg = wsS + OFF_QH  + (size_t)bh * 2048 * 64;
    const unsigned short* Qlg = wsS + OFF_QL  + (size_t)bh * 2048 * 64;
    const unsigned short* Khg = wsS + OFF_KH  + (size_t)bh * 2048 * 64;
    const unsigned short* Klg = wsS + OFF_KL  + (size_t)bh * 2048 * 64;
    const unsigned short* Vhg = wsS + OFF_VTH + (size_t)bh * 64 * 2048;
    const unsigned short* Vlg = wsS + OFF_VTL + (size_t)bh * 64 * 2048;
    const float* Mg = mask + (size_t)b * 2048 * 2048;

    // Q frags in registers: 2 row-strips x 2 k-halves
    bf16x8 qfh[2][2], qfl[2][2];
    #pragma unroll
    for (int mi = 0; mi < 2; ++mi)
        #pragma unroll
        for (int ks = 0; ks < 2; ++ks) {
            const size_t qo = (size_t)(q0 + w * 32 + mi * 16 + lm) * 64 + ks * 32 + quad * 8;
            qfh[mi][ks] = *(const bf16x8*)&Qhg[qo];
            qfl[mi][ks] = *(const bf16x8*)&Qlg[qo];
        }

    const int sk8 = tid & 7;
    const int sr0 = tid >> 3;   // 0..31

    // K/V staging registers (double-buffer)
    bf16x8 rkh[2], rkl[2], rvh[2], rvl[2];
    #pragma unroll
    for (int i = 0; i < 2; ++i) {            // preload tile 0
        const int r = sr0 + 32 * i;
        rkh[i] = *(const bf16x8*)&Khg[(size_t)r * 64 + sk8 * 8];
        rkl[i] = *(const bf16x8*)&Klg[(size_t)r * 64 + sk8 * 8];
        rvh[i] = *(const bf16x8*)&Vhg[(size_t)r * 2048 + sk8 * 8];
        rvl[i] = *(const bf16x8*)&Vlg[(size_t)r * 2048 + sk8 * 8];
    }

    f32x4 o[2][4] = {};
    float lsum[2][4] = {};
    const int qwbase = q0 + w * 32 + quad * 4;   // + mi*16 + j

    for (int k0 = 0; k0 < 2048; k0 += 64) {
        // mask prefetch for THIS tile (L3-resident, overlaps staging+QK)
        float mreg[2][4][4];
        #pragma unroll
        for (int mi = 0; mi < 2; ++mi)
            #pragma unroll
            for (int j = 0; j < 4; ++j)
                #pragma unroll
                for (int ni = 0; ni < 4; ++ni)
                    mreg[mi][j][ni] =
                        Mg[(size_t)(qwbase + mi * 16 + j) * 2048 + k0 + ni * 16 + lm];

        __syncthreads();                      // prev iter's K/V frag reads done
        #pragma unroll
        for (int i = 0; i < 2; ++i) {
            const int r = sr0 + 32 * i;
            *(bf16x8*)&Ksh[sw8(r, sk8)] = rkh[i];
            *(bf16x8*)&Ksl[sw8(r, sk8)] = rkl[i];
            *(bf16x8*)&Vth[sw8(r, sk8)] = rvh[i];
            *(bf16x8*)&Vtl[sw8(r, sk8)] = rvl[i];
        }
        if (k0 + 64 < 2048) {                 // issue NEXT tile's global loads
            #pragma unroll
            for (int i = 0; i < 2; ++i) {
                const int r = sr0 + 32 * i;
                rkh[i] = *(const bf16x8*)&Khg[(size_t)(k0 + 64 + r) * 64 + sk8 * 8];
                rkl[i] = *(const bf16x8*)&Klg[(size_t)(k0 + 64 + r) * 64 + sk8 * 8];
                rvh[i] = *(const bf16x8*)&Vhg[(size_t)r * 2048 + k0 + 64 + sk8 * 8];
                rvl[i] = *(const bf16x8*)&Vlg[(size_t)r * 2048 + k0 + 64 + sk8 * 8];
            }
        }
        __syncthreads();

        // S = Q K^T (split): K frags shared across both row strips
        f32x4 s[2][4] = {};
        #pragma unroll
        for (int ks = 0; ks < 2; ++ks) {
            #pragma unroll
            for (int ni = 0; ni < 4; ++ni) {
                bf16x8 kh = *(const bf16x8*)&Ksh[sw8(ni * 16 + lm, ks * 4 + quad)];
                bf16x8 kl = *(const bf16x8*)&Ksl[sw8(ni * 16 + lm, ks * 4 + quad)];
                #pragma unroll
                for (int mi = 0; mi < 2; ++mi) {
                    s[mi][ni] = __builtin_amdgcn_mfma_f32_16x16x32_bf16(qfh[mi][ks], kh, s[mi][ni], 0, 0, 0);
                    s[mi][ni] = __builtin_amdgcn_mfma_f32_16x16x32_bf16(qfh[mi][ks], kl, s[mi][ni], 0, 0, 0);
                    s[mi][ni] = __builtin_amdgcn_mfma_f32_16x16x32_bf16(qfl[mi][ks], kh, s[mi][ni], 0, 0, 0);
                }
            }
        }

        // p = exp(s * scale * mask); per-lane partial row-sums; P -> LDS split
        #pragma unroll
        for (int mi = 0; mi < 2; ++mi)
            #pragma unroll
            for (int j = 0; j < 4; ++j) {
                #pragma unroll
                for (int ni = 0; ni < 4; ++ni) {
                    const float p = __expf(s[mi][ni][j] * 0.125f * mreg[mi][j][ni]);
                    lsum[mi][j] += p;
                    const short hs = f2b(p);
                    Psh[w][swe(mi * 16 + quad * 4 + j, ni * 16 + lm)] = hs;
                    Psl[w][swe(mi * 16 + quad * 4 + j, ni * 16 + lm)] = f2b(p - b2f(hs));
                }
            }

        // O += P @ V (split); P is this wave's own LDS region (no barrier)
        #pragma unroll
        for (int ks = 0; ks < 2; ++ks) {
            bf16x8 ph[2], pl[2];
            #pragma unroll
            for (int mi = 0; mi < 2; ++mi) {
                ph[mi] = *(const bf16x8*)&Psh[w][sw8(mi * 16 + lm, ks * 4 + quad)];
                pl[mi] = *(const bf16x8*)&Psl[w][sw8(mi * 16 + lm, ks * 4 + quad)];
            }
            #pragma unroll
            for (int ni = 0; ni < 4; ++ni) {
                bf16x8 vh = *(const bf16x8*)&Vth[sw8(ni * 16 + lm, ks * 4 + quad)];
                bf16x8 vl = *(const bf16x8*)&Vtl[sw8(ni * 16 + lm, ks * 4 + quad)];
                #pragma unroll
                for (int mi = 0; mi < 2; ++mi) {
                    o[mi][ni] = __builtin_amdgcn_mfma_f32_16x16x32_bf16(ph[mi], vh, o[mi][ni], 0, 0, 0);
                    o[mi][ni] = __builtin_amdgcn_mfma_f32_16x16x32_bf16(ph[mi], vl, o[mi][ni], 0, 0, 0);
                    o[mi][ni] = __builtin_amdgcn_mfma_f32_16x16x32_bf16(pl[mi], vh, o[mi][ni], 0, 0, 0);
                }
            }
        }
    }

    // epilogue: one cross-lane row-sum reduction, normalize, split-store concat
    #pragma unroll
    for (int mi = 0; mi < 2; ++mi)
        #pragma unroll
        for (int j = 0; j < 4; ++j) {
            float ls = lsum[mi][j];
            ls += __shfl_xor(ls, 1);
            ls += __shfl_xor(ls, 2);
            ls += __shfl_xor(ls, 4);
            ls += __shfl_xor(ls, 8);
            const float inv = 1.0f / ls;
            const int q = qwbase + mi * 16 + j;
            #pragma unroll
            for (int ni = 0; ni < 4; ++ni) {
                const float val = o[mi][ni][j] * inv;
                const size_t idx = ((size_t)b * 2048 + q) * 1024 + h * 64 + ni * 16 + lm;
                const short hs = f2b(val);
                ch[idx] = hs;
                cl[idx] = f2b(val - b2f(hs));
            }
        }
}

extern "C" void kernel_launch(void* const* d_in, const int* in_sizes, int n_in,
                              void* d_out, int out_size, void* d_ws, size_t ws_size,
                              hipStream_t stream) {
    const float* x    = (const float*)d_in[0];
    const float* mask = (const float*)d_in[1];
    const float* Wq   = (const float*)d_in[2];
    const float* bq   = (const float*)d_in[3];
    const float* Wk   = (const float*)d_in[4];
    const float* bk   = (const float*)d_in[5];
    const float* Wv   = (const float*)d_in[6];
    const float* bv   = (const float*)d_in[7];
    const float* Wo   = (const float*)d_in[8];
    const float* bo   = (const float*)d_in[9];

    unsigned short* wsS = (unsigned short*)d_ws;
    const bool presplitX = ws_size >= WS_FULL_BYTES;   // constant across calls

    // 1. pre-split weights (+ x if workspace allows)
    if (presplitX) {
        split_wx<<<8192, 256, 0, stream>>>(Wq, Wk, Wv, Wo, x,
            wsS + OFF_WH, wsS + OFF_WL, wsS + OFF_XH, wsS + OFF_XL);
    } else {
        split_wx<<<4096, 256, 0, stream>>>(Wq, Wk, Wv, Wo, x,
            wsS + OFF_WH, wsS + OFF_WL, nullptr, nullptr);
    }

    // 2. Q/K/V projections (split-bf16 MFMA)
    gemm_split<<<dim3(8, 32, 3), 256, 0, stream>>>(
        presplitX ? nullptr : x,
        presplitX ? wsS + OFF_XH : nullptr,
        presplitX ? wsS + OFF_XL : nullptr,
        wsS, bq, bk, bv, bo, nullptr, 0);

    // 3. fused masked-softmax flash attention (128-row blocks, 2/CU exact)
    attn_fast<<<dim3(16, 16, 2), 256, 0, stream>>>(
        wsS, mask, wsS + OFF_CH, wsS + OFF_CL);

    // 4. output projection (pre-split concat planes)
    gemm_split<<<dim3(8, 32, 1), 256, 0, stream>>>(
        nullptr, wsS + OFF_CH, wsS + OFF_CL,
        wsS, bq, bk, bv, bo, (float*)d_out, 3);
}

// Round 7
// 289.765 us; speedup vs baseline: 2.0036x; 2.0036x over previous
//
#include <hip/hip_runtime.h>
#include <hip/hip_bf16.h>
#include <math.h>

// B=2, N=2048, M=1024, H=16, DK=64. fp32 in/out.
// R7 = R4's proven structure + term-reduced split-bf16:
//   GEMMs:  a*w ~= (ah+al)*wh        (2 MFMA; W hi-only, error ~2^-9 rel)
//   QK:     s   ~= (qh+ql)*kh        (2 MFMA; K hi-only)
//   PV:     o   ~= ph*vh             (1 MFMA; post-softmax, damped 1/sqrt(N))
// All GEMM staging is pure b128 copies from pre-split planes (no hot VALU).
// attn LDS 24KB -> 4 blocks/CU; gemm LDS 48KB -> 3 blocks/CU.

typedef __attribute__((ext_vector_type(8))) short bf16x8;
typedef __attribute__((ext_vector_type(4))) float f32x4;

__device__ __forceinline__ short f2b(float f) {
    union { __hip_bfloat16 h; short s; } u;
    u.h = __float2bfloat16(f);   // RNE
    return u.s;
}
__device__ __forceinline__ float b2f(short s) {
    union { short s; __hip_bfloat16 h; } u;
    u.s = s;
    return __bfloat162float(u.h);
}

// XOR-swizzled element offset inside a [rows][64]-bf16 tile (16B blocks).
__device__ __forceinline__ int sw8(int r, int k8) {       // k8 = octet 0..7
    return (r << 6) + ((k8 ^ (r & 7)) << 3);
}
__device__ __forceinline__ int swe(int r, int k) {        // element-level
    return (r << 6) + (((k >> 3) ^ (r & 7)) << 3) + (k & 7);
}

// workspace layout (SHORT offsets). Every plane = 4194304 shorts (8 MB).
// 9 planes = 75.5 MB  (< 83.9 MB proven available in R3/R4)
#define PLANE   4194304UL
#define OFF_WH  (0UL * PLANE)    // [4][1024][1024] W hi (Wq|Wk|Wv|Wo)
#define OFF_XH  (1UL * PLANE)    // [4096][1024] x hi
#define OFF_XL  (2UL * PLANE)    // x lo
#define OFF_QH  (3UL * PLANE)    // [B,H,N,DK]
#define OFF_QL  (4UL * PLANE)
#define OFF_KH  (5UL * PLANE)    // hi only
#define OFF_VTH (6UL * PLANE)    // [B,H,DK,N] hi only
#define OFF_CH  (7UL * PLANE)    // [B,N,M] concat hi
#define OFF_CL  (8UL * PLANE)    // concat lo

// ---------------------------------------------------------------------------
// Pre-split: W -> hi only; x -> hi + lo.
// ---------------------------------------------------------------------------
__global__ __launch_bounds__(256) void split_wx(
    const float* __restrict__ Wq, const float* __restrict__ Wk,
    const float* __restrict__ Wv, const float* __restrict__ Wo,
    const float* __restrict__ x,
    unsigned short* __restrict__ wh,
    unsigned short* __restrict__ xh, unsigned short* __restrict__ xl)
{
    const int i = blockIdx.x * 256 + threadIdx.x;   // float4 idx, 2097152 total
    if (i < 1048576) {                               // weights: hi only
        const float* src = (i < 262144) ? Wq : (i < 524288) ? Wk
                         : (i < 786432) ? Wv : Wo;
        const int local = i & 262143;
        float4 v = ((const float4*)src)[local];
        short4 h;
        h.x = f2b(v.x); h.y = f2b(v.y); h.z = f2b(v.z); h.w = f2b(v.w);
        ((short4*)(wh + (size_t)(i >> 18) * 1048576))[local] = h;
    } else {                                         // x: hi + lo
        const int local = i - 1048576;
        float4 v = ((const float4*)x)[local];
        short4 h, l;
        h.x = f2b(v.x); l.x = f2b(v.x - b2f(h.x));
        h.y = f2b(v.y); l.y = f2b(v.y - b2f(h.y));
        h.z = f2b(v.z); l.z = f2b(v.z - b2f(h.z));
        h.w = f2b(v.w); l.w = f2b(v.w - b2f(h.w));
        ((short4*)xh)[local] = h;
        ((short4*)xl)[local] = l;
    }
}

// ---------------------------------------------------------------------------
// 2-term split GEMM: C = A @ W^T + bias,  A = Ah + Al (planes), W = Wh only.
// 128x128 tile, 256 thr (4 waves 2x2), 4x4 16x16x32 frags, BK=64, LDS 48KB.
// mode 0: Q (hi+lo out), 1: K (hi), 2: V^T (hi), 3: fp32 out + bias.
// ---------------------------------------------------------------------------
__global__ __launch_bounds__(256, 3) void gemm_split(
    const unsigned short* __restrict__ Ah, const unsigned short* __restrict__ Al,
    unsigned short* __restrict__ wsS,
    const float* __restrict__ b0, const float* __restrict__ b1,
    const float* __restrict__ b2, const float* __restrict__ b3,
    float* __restrict__ oout, int modeBase)
{
    __shared__ unsigned short Ash[128 * 64], Asl[128 * 64];
    __shared__ unsigned short Bsh[128 * 64];

    const int mode = modeBase + blockIdx.z;
    const unsigned short* Wh = wsS + OFF_WH + (size_t)mode * 1048576;
    const float* bias = (mode == 0) ? b0 : (mode == 1) ? b1 : (mode == 2) ? b2 : b3;

    const int tid  = threadIdx.x;
    const int lane = tid & 63;
    const int lm   = lane & 15;
    const int quad = lane >> 4;
    const int w    = tid >> 6;
    const int wr   = w >> 1, wc = w & 1;

    const int row0 = blockIdx.y * 128;
    const int col0 = blockIdx.x * 128;

    const int sk8 = tid & 7;      // staging octet
    const int sr0 = tid >> 3;     // staging row 0..31

    f32x4 acc[4][4] = {};

    for (int k0 = 0; k0 < 1024; k0 += 64) {
        if (k0) __syncthreads();
        #pragma unroll
        for (int i = 0; i < 4; ++i) {
            const int r = sr0 + 32 * i;
            *(bf16x8*)&Ash[sw8(r, sk8)] =
                *(const bf16x8*)&Ah[(size_t)(row0 + r) * 1024 + k0 + sk8 * 8];
            *(bf16x8*)&Asl[sw8(r, sk8)] =
                *(const bf16x8*)&Al[(size_t)(row0 + r) * 1024 + k0 + sk8 * 8];
            *(bf16x8*)&Bsh[sw8(r, sk8)] =
                *(const bf16x8*)&Wh[(size_t)(col0 + r) * 1024 + k0 + sk8 * 8];
        }
        __syncthreads();
        #pragma unroll
        for (int ks = 0; ks < 2; ++ks) {
            bf16x8 afh[4], afl[4], bfh[4];
            #pragma unroll
            for (int mi = 0; mi < 4; ++mi) {
                afh[mi] = *(const bf16x8*)&Ash[sw8(wr * 64 + mi * 16 + lm, ks * 4 + quad)];
                afl[mi] = *(const bf16x8*)&Asl[sw8(wr * 64 + mi * 16 + lm, ks * 4 + quad)];
            }
            #pragma unroll
            for (int ni = 0; ni < 4; ++ni)
                bfh[ni] = *(const bf16x8*)&Bsh[sw8(wc * 64 + ni * 16 + lm, ks * 4 + quad)];
            #pragma unroll
            for (int mi = 0; mi < 4; ++mi) {
                #pragma unroll
                for (int ni = 0; ni < 4; ++ni) {
                    acc[mi][ni] = __builtin_amdgcn_mfma_f32_16x16x32_bf16(
                        afh[mi], bfh[ni], acc[mi][ni], 0, 0, 0);
                    acc[mi][ni] = __builtin_amdgcn_mfma_f32_16x16x32_bf16(
                        afl[mi], bfh[ni], acc[mi][ni], 0, 0, 0);
                }
            }
        }
    }

    unsigned short* qh  = wsS + OFF_QH;
    unsigned short* ql  = wsS + OFF_QL;
    unsigned short* kh  = wsS + OFF_KH;
    unsigned short* vth = wsS + OFF_VTH;

    // epilogue: C/D layout col=lane&15, row=quad*4+reg
    #pragma unroll
    for (int ni = 0; ni < 4; ++ni) {
        const int f = col0 + wc * 64 + ni * 16 + lm;
        const float bv = bias[f];
        const int h = f >> 6, d = f & 63;
        #pragma unroll
        for (int mi = 0; mi < 4; ++mi) {
            #pragma unroll
            for (int j = 0; j < 4; ++j) {
                const int row = row0 + wr * 64 + mi * 16 + quad * 4 + j;
                const float val = acc[mi][ni][j] + bv;
                if (mode == 3) {
                    oout[(size_t)row * 1024 + f] = val;
                } else {
                    const int bb = row >> 11, n = row & 2047;
                    const short hs = f2b(val);
                    if (mode == 2) {
                        vth[((size_t)(bb * 16 + h) * 64 + d) * 2048 + n] = hs;
                    } else {
                        const size_t idx = ((size_t)(bb * 16 + h) * 2048 + n) * 64 + d;
                        if (mode == 0) { qh[idx] = hs; ql[idx] = f2b(val - b2f(hs)); }
                        else           { kh[idx] = hs; }
                    }
                }
            }
        }
    }
}

// ---------------------------------------------------------------------------
// Flash attention (R4 64-row structure), deferred softmax normalization.
// QK 2-term (q-split x K-hi), PV 1-term (P-hi x V-hi). LDS 24KB.
// Block = (b, h, 64 q-rows); wave w owns q-strip w*16..+16.
// Output: concat hi/lo planes for the 2-term out_gemm.
// ---------------------------------------------------------------------------
__global__ __launch_bounds__(256, 4) void attn_fast(
    const unsigned short* __restrict__ wsS, const float* __restrict__ mask,
    unsigned short* __restrict__ ch, unsigned short* __restrict__ cl)
{
    __shared__ unsigned short Ksh[64 * 64];      // [kcol][d] hi
    __shared__ unsigned short Vth[64 * 64];      // [d][k]    hi
    __shared__ unsigned short Psh[4][16 * 64];   // per-wave [q][k] hi

    const int tid  = threadIdx.x;
    const int lane = tid & 63;
    const int lm   = lane & 15;
    const int quad = lane >> 4;
    const int w    = tid >> 6;

    const int q0 = blockIdx.x * 64;
    const int h  = blockIdx.y;
    const int b  = blockIdx.z;
    const int bh = b * 16 + h;

    const unsigned short* Qhg = wsS + OFF_QH  + (size_t)bh * 2048 * 64;
    const unsigned short* Qlg = wsS + OFF_QL  + (size_t)bh * 2048 * 64;
    const unsigned short* Khg = wsS + OFF_KH  + (size_t)bh * 2048 * 64;
    const unsigned short* Vhg = wsS + OFF_VTH + (size_t)bh * 64 * 2048;
    const float* Mg = mask + (size_t)b * 2048 * 2048;

    // Q frags in registers (this wave's 16 q-rows)
    bf16x8 qfh[2], qfl[2];
    #pragma unroll
    for (int ks = 0; ks < 2; ++ks) {
        const size_t qo = (size_t)(q0 + w * 16 + lm) * 64 + ks * 32 + quad * 8;
        qfh[ks] = *(const bf16x8*)&Qhg[qo];
        qfl[ks] = *(const bf16x8*)&Qlg[qo];
    }

    const int sk8 = tid & 7;
    const int sr0 = tid >> 3;   // 0..31

    // K/V staging registers (double-buffer), hi planes only
    bf16x8 rkh[2], rvh[2];
    #pragma unroll
    for (int i = 0; i < 2; ++i) {            // preload tile 0
        const int r = sr0 + 32 * i;
        rkh[i] = *(const bf16x8*)&Khg[(size_t)r * 64 + sk8 * 8];
        rvh[i] = *(const bf16x8*)&Vhg[(size_t)r * 2048 + sk8 * 8];
    }

    f32x4 o[4] = {};
    float lsum[4] = {0.f, 0.f, 0.f, 0.f};
    const int qwbase = q0 + w * 16 + quad * 4;

    for (int k0 = 0; k0 < 2048; k0 += 64) {
        // mask prefetch for THIS tile
        float mreg[4][4];
        #pragma unroll
        for (int j = 0; j < 4; ++j)
            #pragma unroll
            for (int ni = 0; ni < 4; ++ni)
                mreg[j][ni] = Mg[(size_t)(qwbase + j) * 2048 + k0 + ni * 16 + lm];

        __syncthreads();                      // prev iter's K/V frag reads done
        #pragma unroll
        for (int i = 0; i < 2; ++i) {
            const int r = sr0 + 32 * i;
            *(bf16x8*)&Ksh[sw8(r, sk8)] = rkh[i];
            *(bf16x8*)&Vth[sw8(r, sk8)] = rvh[i];
        }
        if (k0 + 64 < 2048) {                 // issue NEXT tile's global loads
            #pragma unroll
            for (int i = 0; i < 2; ++i) {
                const int r = sr0 + 32 * i;
                rkh[i] = *(const bf16x8*)&Khg[(size_t)(k0 + 64 + r) * 64 + sk8 * 8];
                rvh[i] = *(const bf16x8*)&Vhg[(size_t)r * 2048 + k0 + 64 + sk8 * 8];
            }
        }
        __syncthreads();

        // S ~= (qh+ql) K_hi^T : 2 MFMA per (ks,ni)
        f32x4 s[4] = {};
        #pragma unroll
        for (int ks = 0; ks < 2; ++ks) {
            #pragma unroll
            for (int ni = 0; ni < 4; ++ni) {
                bf16x8 kh = *(const bf16x8*)&Ksh[sw8(ni * 16 + lm, ks * 4 + quad)];
                s[ni] = __builtin_amdgcn_mfma_f32_16x16x32_bf16(qfh[ks], kh, s[ni], 0, 0, 0);
                s[ni] = __builtin_amdgcn_mfma_f32_16x16x32_bf16(qfl[ks], kh, s[ni], 0, 0, 0);
            }
        }

        // p = exp(s * scale * mask); per-lane partial row-sums; P(hi) -> LDS
        #pragma unroll
        for (int j = 0; j < 4; ++j) {
            #pragma unroll
            for (int ni = 0; ni < 4; ++ni) {
                const float p = __expf(s[ni][j] * 0.125f * mreg[j][ni]);
                lsum[j] += p;
                Psh[w][swe(quad * 4 + j, ni * 16 + lm)] = f2b(p);
            }
        }

        // O += P_hi @ V_hi : 1 MFMA per (ks,ni); own-wave LDS, no barrier
        #pragma unroll
        for (int ks = 0; ks < 2; ++ks) {
            bf16x8 ph = *(const bf16x8*)&Psh[w][sw8(lm, ks * 4 + quad)];
            #pragma unroll
            for (int ni = 0; ni < 4; ++ni) {
                bf16x8 vh = *(const bf16x8*)&Vth[sw8(ni * 16 + lm, ks * 4 + quad)];
                o[ni] = __builtin_amdgcn_mfma_f32_16x16x32_bf16(ph, vh, o[ni], 0, 0, 0);
            }
        }
    }

    // epilogue: one cross-lane row-sum reduction, normalize, split-store concat
    #pragma unroll
    for (int j = 0; j < 4; ++j) {
        float ls = lsum[j];
        ls += __shfl_xor(ls, 1);
        ls += __shfl_xor(ls, 2);
        ls += __shfl_xor(ls, 4);
        ls += __shfl_xor(ls, 8);
        const float inv = 1.0f / ls;
        const int q = qwbase + j;
        #pragma unroll
        for (int ni = 0; ni < 4; ++ni) {
            const float val = o[ni][j] * inv;
            const size_t idx = ((size_t)b * 2048 + q) * 1024 + h * 64 + ni * 16 + lm;
            const short hs = f2b(val);
            ch[idx] = hs;
            cl[idx] = f2b(val - b2f(hs));
        }
    }
}

extern "C" void kernel_launch(void* const* d_in, const int* in_sizes, int n_in,
                              void* d_out, int out_size, void* d_ws, size_t ws_size,
                              hipStream_t stream) {
    const float* x    = (const float*)d_in[0];
    const float* mask = (const float*)d_in[1];
    const float* Wq   = (const float*)d_in[2];
    const float* bq   = (const float*)d_in[3];
    const float* Wk   = (const float*)d_in[4];
    const float* bk   = (const float*)d_in[5];
    const float* Wv   = (const float*)d_in[6];
    const float* bv   = (const float*)d_in[7];
    const float* Wo   = (const float*)d_in[8];
    const float* bo   = (const float*)d_in[9];

    unsigned short* wsS = (unsigned short*)d_ws;

    // 1. pre-split: W -> hi; x -> hi+lo
    split_wx<<<8192, 256, 0, stream>>>(Wq, Wk, Wv, Wo, x,
        wsS + OFF_WH, wsS + OFF_XH, wsS + OFF_XL);

    // 2. Q/K/V projections (2-term split MFMA, pure-copy staging)
    gemm_split<<<dim3(8, 32, 3), 256, 0, stream>>>(
        wsS + OFF_XH, wsS + OFF_XL, wsS, bq, bk, bv, bo, nullptr, 0);

    // 3. fused masked-softmax flash attention (QK 2-term, PV 1-term)
    attn_fast<<<dim3(32, 16, 2), 256, 0, stream>>>(
        wsS, mask, wsS + OFF_CH, wsS + OFF_CL);

    // 4. output projection (2-term)
    gemm_split<<<dim3(8, 32, 1), 256, 0, stream>>>(
        wsS + OFF_CH, wsS + OFF_CL, wsS, bq, bk, bv, bo, (float*)d_out, 3);
}